// Round 10
// baseline (177.614 us; speedup 1.0000x reference)
//
#include <hip/hip_runtime.h>
#include <hip/hip_bf16.h>
#include <cstdint>

#define N_PTS 8192
#define DIM 128
// 32-row x 64-col wave tiles over the upper triangle (as r7-r9, verified).
#define NBLK 16512
#define THRESH 48.0f  // base-2 skip margin: dropped mass < 2^25 * 2^-48 = 2^-23 rel

// Base-2-domain circle-loss constants (gamma=256, m=0.25, folded log2(e)).
#define KC2 369.3299304675746f    //  256*log2e
#define KC1 -738.6598609351493f   // -512*log2e
#define KC0 346.2468098133512f    //  240*log2e
#define KCN0 -23.083120654223414f // -16*log2e
#define NEGH -1e30f
#define LN2F 0.6931471805599453f

typedef __attribute__((ext_vector_type(8))) __bf16 bf16x8;
typedef __attribute__((ext_vector_type(4))) float f32x4;

// RNE float -> bf16 bits (inputs are finite)
__device__ __forceinline__ unsigned short f2bf(float x) {
  unsigned int u = __float_as_uint(x);
  unsigned int r = (u + 0x7FFFu + ((u >> 16) & 1u)) >> 16;
  return (unsigned short)r;
}
// order-preserving float<->uint for atomicMax on floats
__device__ __forceinline__ unsigned int encf(float f) {
  unsigned int u = __float_as_uint(f);
  return (u & 0x80000000u) ? ~u : (u | 0x80000000u);
}
__device__ __forceinline__ float decf(unsigned int u) {
  return __uint_as_float((u & 0x80000000u) ? (u & 0x7FFFFFFFu) : ~u);
}

// L2-normalize rows -> bf16; pack labels to u8; init the 128 atomicMax slots.
__global__ __launch_bounds__(256) void normalize_kernel(const float* __restrict__ feat,
                                                        const int* __restrict__ labels,
                                                        unsigned short* __restrict__ fb,
                                                        unsigned char* __restrict__ lab8,
                                                        unsigned int* __restrict__ slots) {
  const int gid = blockIdx.x * 256 + threadIdx.x;
  if (gid < N_PTS) lab8[gid] = (unsigned char)labels[gid];
  if (blockIdx.x == 0 && threadIdx.x < 128) slots[threadIdx.x] = encf(NEGH);
  const int row = blockIdx.x * 8 + (threadIdx.x >> 5);
  const int l32 = threadIdx.x & 31;
  const float4 v = *(const float4*)(feat + row * DIM + l32 * 4);
  float ss = v.x * v.x + v.y * v.y + v.z * v.z + v.w * v.w;
#pragma unroll
  for (int o = 16; o > 0; o >>= 1) ss += __shfl_xor(ss, o);
  const float inv = 1.0f / fmaxf(sqrtf(ss), 1e-12f);
  uint2 pack;
  pack.x = (unsigned int)f2bf(v.x * inv) | ((unsigned int)f2bf(v.y * inv) << 16);
  pack.y = (unsigned int)f2bf(v.z * inv) | ((unsigned int)f2bf(v.w * inv) << 16);
  *(uint2*)(fb + row * DIM + l32 * 4) = pack;
}

// ---- shared tile machinery (verified r7-r9) ----
#define OFFI(I) (128 * (I) - (((I) - 1) * ((I) - 1)) / 4)
#define DECODE(TID, IV, JV)                                              \
  do {                                                                   \
    int _i = (int)(2.0f * (128.5f - sqrtf(16512.0f - (float)(TID))));    \
    _i = _i < 0 ? 0 : (_i > 255 ? 255 : _i);                             \
    while (OFFI(_i) > (TID)) --_i;                                       \
    while (OFFI(_i + 1) <= (TID)) ++_i;                                  \
    IV = _i;                                                             \
    JV = (_i >> 1) + ((TID)-OFFI(_i));                                   \
  } while (0)

#define KLOOP(PA, PB, ACC)                                               \
  _Pragma("unroll 1") for (int kk = 0; kk < 4; ++kk) {                   \
    bf16x8 fa[2], fbv[4];                                                \
    _Pragma("unroll") for (int x = 0; x < 2; ++x)                        \
        fa[x] = *(const bf16x8*)((PA) + x * 16 * DIM + kk * 32);         \
    _Pragma("unroll") for (int x = 0; x < 4; ++x)                        \
        fbv[x] = *(const bf16x8*)((PB) + x * 16 * DIM + kk * 32);        \
    _Pragma("unroll") for (int tm = 0; tm < 2; ++tm)                     \
        _Pragma("unroll") for (int tn = 0; tn < 4; ++tn)                 \
            ACC[tm][tn] = __builtin_amdgcn_mfma_f32_16x16x32_bf16(       \
                fa[tm], fbv[tn], ACC[tm][tn], 0, 0, 0);                  \
  }

// Phase A: GEMM + MAX-ONLY epilogue. Positives: lp monotone-decreasing in s,
// so track smin (2 ops/elem) and evaluate lp once. Negatives: ~6 ops/elem.
// No exp2, no sums, half the shuffle chains. Tile (Mp,Mn) -> tmax; global
// maxes via 128-slot encoded atomicMax (64 p + 64 n, indexed tid&63).
__global__ __launch_bounds__(256) void pair_max_kernel(const unsigned short* __restrict__ f,
                                                       const unsigned char* __restrict__ lab8,
                                                       float2* __restrict__ tmax,
                                                       unsigned int* __restrict__ slots) {
  const int lane = threadIdx.x & 63;
  const int tid = blockIdx.x * 4 + (threadIdx.x >> 6);
  int I, J;
  DECODE(tid, I, J);

  const int rsel = lane & 15, kgrp = lane >> 4;
  const unsigned short* pA = f + (size_t)(I * 32 + rsel) * DIM + kgrp * 8;
  const unsigned short* pB = f + (size_t)(J * 64 + rsel) * DIM + kgrp * 8;

  const int ibase = I * 32 + kgrp * 4, jbase = J * 64 + rsel;
  unsigned int liPack[2], ljPack = 0;
#pragma unroll
  for (int tn = 0; tn < 4; ++tn)
    ljPack |= ((unsigned int)lab8[jbase + tn * 16]) << (tn * 8);
#pragma unroll
  for (int tm = 0; tm < 2; ++tm)
    liPack[tm] = *(const unsigned int*)(lab8 + ibase + tm * 16);

  f32x4 acc[2][4];
#pragma unroll
  for (int a = 0; a < 2; ++a)
#pragma unroll
    for (int b = 0; b < 4; ++b) acc[a][b] = (f32x4){0.f, 0.f, 0.f, 0.f};
  KLOOP(pA, pB, acc);

  // C/D mapping: col = lane&15, row = (lane>>4)*4 + reg
  float smin = 1e30f, mn = NEGH;
  if (2 * J > I) {  // fully above diagonal: all pairs valid
#pragma unroll
    for (int tm = 0; tm < 2; ++tm)
#pragma unroll
      for (int tn = 0; tn < 4; ++tn) {
        const unsigned int ljB = (ljPack >> (tn * 8)) & 0xFFu;
#pragma unroll
        for (int r = 0; r < 4; ++r) {
          const float s = acc[tm][tn][r];
          const bool eq = (((liPack[tm] >> (r * 8)) & 0xFFu) == ljB);
          smin = fminf(smin, eq ? s : 1e30f);
          float q = fmaf(s * s, KC2, KCN0);     // base-2 ln (unclamped)
          q = (s > -0.25f) ? q : 0.f;           // clamp branch -> logit 0
          mn = fmaxf(mn, eq ? NEGH : q);
        }
      }
  } else {  // diagonal-straddling: valid iff col > row
#pragma unroll
    for (int tm = 0; tm < 2; ++tm)
#pragma unroll
      for (int tn = 0; tn < 4; ++tn) {
        const unsigned int ljB = (ljPack >> (tn * 8)) & 0xFFu;
        const int d = (jbase + tn * 16) - (ibase + tm * 16);  // valid iff d > r
#pragma unroll
        for (int r = 0; r < 4; ++r) {
          const float s = acc[tm][tn][r];
          const bool eq = (((liPack[tm] >> (r * 8)) & 0xFFu) == ljB);
          const bool valid = d > r;
          smin = fminf(smin, (eq && valid) ? s : 1e30f);
          float q = fmaf(s * s, KC2, KCN0);
          q = (s > -0.25f) ? q : 0.f;
          mn = fmaxf(mn, (!eq && valid) ? q : NEGH);
        }
      }
  }
#pragma unroll
  for (int o = 32; o > 0; o >>= 1) {
    smin = fminf(smin, __shfl_xor(smin, o));
    mn = fmaxf(mn, __shfl_xor(mn, o));
  }
  // lp monotone-decreasing in s: tile Mp = lp(smin); sentinel if no positive
  const float Mp_t = (smin < 2.f) ? fmaf(smin, fmaf(smin, KC2, KC1), KC0) : -1e28f;
  const float Mn_t = fmaxf(mn, -1e28f);
  if (lane == 0) {
    tmax[tid] = make_float2(Mp_t, Mn_t);
    atomicMax(&slots[tid & 63], encf(Mp_t));
    atomicMax(&slots[64 + (tid & 63)], encf(Mn_t));
  }
}

// Phase B: read global maxes (64-slot wave reduce), early-exit tiles that
// cannot contribute >= 2^-48 relative; ~2% of tiles redo the cheap GEMM and
// sum exp2 against the GLOBAL maxes (no per-tile max merge needed).
__global__ __launch_bounds__(256) void pair_sum_kernel(const unsigned short* __restrict__ f,
                                                       const unsigned char* __restrict__ lab8,
                                                       const float2* __restrict__ tmax,
                                                       const unsigned int* __restrict__ slots,
                                                       float2* __restrict__ tsum) {
  const int lane = threadIdx.x & 63;
  const int tid = blockIdx.x * 4 + (threadIdx.x >> 6);

  float vp = decf(slots[lane]), vn = decf(slots[64 + lane]);
#pragma unroll
  for (int o = 32; o > 0; o >>= 1) {
    vp = fmaxf(vp, __shfl_xor(vp, o));
    vn = fmaxf(vn, __shfl_xor(vn, o));
  }
  const float Mpg = vp, Mng = vn;  // global base-2 maxes

  const float2 tmv = tmax[tid];
  if (tmv.x < Mpg - THRESH && tmv.y < Mng - THRESH) {
    if (lane == 0) tsum[tid] = make_float2(0.f, 0.f);
    return;
  }

  int I, J;
  DECODE(tid, I, J);
  const int rsel = lane & 15, kgrp = lane >> 4;
  const unsigned short* pA = f + (size_t)(I * 32 + rsel) * DIM + kgrp * 8;
  const unsigned short* pB = f + (size_t)(J * 64 + rsel) * DIM + kgrp * 8;
  const int ibase = I * 32 + kgrp * 4, jbase = J * 64 + rsel;
  unsigned int liPack[2], ljPack = 0;
#pragma unroll
  for (int tn = 0; tn < 4; ++tn)
    ljPack |= ((unsigned int)lab8[jbase + tn * 16]) << (tn * 8);
#pragma unroll
  for (int tm = 0; tm < 2; ++tm)
    liPack[tm] = *(const unsigned int*)(lab8 + ibase + tm * 16);

  f32x4 acc[2][4];
#pragma unroll
  for (int a = 0; a < 2; ++a)
#pragma unroll
    for (int b = 0; b < 4; ++b) acc[a][b] = (f32x4){0.f, 0.f, 0.f, 0.f};
  KLOOP(pA, pB, acc);

  const bool alldiag = !(2 * J > I);
  float sp = 0.f, sn = 0.f;
#pragma unroll
  for (int tm = 0; tm < 2; ++tm)
#pragma unroll
    for (int tn = 0; tn < 4; ++tn) {
      const unsigned int ljB = (ljPack >> (tn * 8)) & 0xFFu;
      const int d = (jbase + tn * 16) - (ibase + tm * 16);
#pragma unroll
      for (int r = 0; r < 4; ++r) {
        const float s = acc[tm][tn][r];
        const bool eq = (((liPack[tm] >> (r * 8)) & 0xFFu) == ljB);
        float u = fmaf(s, fmaf(s, KC2, eq ? KC1 : 0.f), eq ? KC0 : KCN0);
        u = (!eq && s <= -0.25f) ? 0.f : u;
        const bool valid = !alldiag ? true : (d > r);
        u = valid ? u : NEGH;
        const float e = __builtin_amdgcn_exp2f(u - (eq ? Mpg : Mng));
        sp += eq ? e : 0.f;
        sn += eq ? 0.f : e;
      }
    }
#pragma unroll
  for (int o = 32; o > 0; o >>= 1) {
    sp += __shfl_xor(sp, o);
    sn += __shfl_xor(sn, o);
  }
  if (lane == 0) tsum[tid] = make_float2(sp, sn);
}

// Deterministic fixed-order reduce of per-tile sums + softplus.
__global__ __launch_bounds__(1024) void final_kernel(const float2* __restrict__ tsum,
                                                     const unsigned int* __restrict__ slots,
                                                     float* __restrict__ out) {
  const int t = threadIdx.x;
  float sp = 0.f, sn = 0.f;
  for (int i = t; i < NBLK; i += 1024) {
    const float2 v = tsum[i];
    sp += v.x;
    sn += v.y;
  }
  __shared__ float ap[1024], an[1024];
  ap[t] = sp; an[t] = sn;
  __syncthreads();
  for (int off = 512; off > 0; off >>= 1) {
    if (t < off) { ap[t] += ap[t + off]; an[t] += an[t + off]; }
    __syncthreads();
  }
  if (t == 0) {
    float Mpg = NEGH, Mng = NEGH;
    for (int i = 0; i < 64; ++i) {
      Mpg = fmaxf(Mpg, decf(slots[i]));
      Mng = fmaxf(Mng, decf(slots[64 + i]));
    }
    const float lsep = (Mpg + __builtin_amdgcn_logf(ap[0])) * LN2F;  // base-2 -> nat
    const float lsen = (Mng + __builtin_amdgcn_logf(an[0])) * LN2F;
    const float x = lsep + lsen;
    out[0] = fmaxf(x, 0.f) + log1pf(__expf(-fabsf(x)));  // stable softplus
  }
}

extern "C" void kernel_launch(void* const* d_in, const int* in_sizes, int n_in,
                              void* d_out, int out_size, void* d_ws, size_t ws_size,
                              hipStream_t stream) {
  const float* feat = (const float*)d_in[0];
  const int* labels = (const int*)d_in[1];
  float* out = (float*)d_out;

  char* base = (char*)d_ws;
  unsigned short* fb = (unsigned short*)base;                        // 2 MiB
  unsigned char* lab8 = (unsigned char*)(base + 2097152);            // 8 KiB
  float2* tmax = (float2*)(base + 2105344);                          // 129 KiB
  float2* tsum = (float2*)(base + 2237440);                          // 129 KiB
  unsigned int* slots = (unsigned int*)(base + 2369536);             // 512 B

  normalize_kernel<<<N_PTS / 8, 256, 0, stream>>>(feat, labels, fb, lab8, slots);
  pair_max_kernel<<<NBLK / 4, 256, 0, stream>>>(fb, lab8, tmax, slots);
  pair_sum_kernel<<<NBLK / 4, 256, 0, stream>>>(fb, lab8, tmax, slots, tsum);
  final_kernel<<<1, 1024, 0, stream>>>(tsum, slots, out);
}

// Round 11
// 94.782 us; speedup vs baseline: 1.8739x; 1.8739x over previous
//
#include <hip/hip_runtime.h>
#include <hip/hip_bf16.h>
#include <cstdint>

#define N_PTS 8192
#define DIM 128
// 32-row x 64-col wave tiles over the upper triangle (verified r7-r10).
// Row-tiles I in [0,256), col-tiles J in [0,128), jmin(I) = I>>1.
#define NBLK 16512

// Base-2-domain circle-loss constants (gamma=256, m=0.25, folded log2(e)).
#define KC2 369.3299304675746f    //  256*log2e
#define KC1 -738.6598609351493f   // -512*log2e
#define KC0 346.2468098133512f    //  240*log2e
#define KCN0 -23.083120654223414f // -16*log2e
#define NEGH -1e30f
#define LN2F 0.6931471805599453f

typedef __attribute__((ext_vector_type(8))) __bf16 bf16x8;
typedef __attribute__((ext_vector_type(4))) float f32x4;

// RNE float -> bf16 bits (inputs are finite, no NaN handling needed)
__device__ __forceinline__ unsigned short f2bf(float x) {
  unsigned int u = __float_as_uint(x);
  unsigned int r = (u + 0x7FFFu + ((u >> 16) & 1u)) >> 16;
  return (unsigned short)r;
}

// PANEL-SWIZZLED feature layout (the round-10 fix).
// Panels of 16 rows. Within panel p (elems): [kk:4][kgrp:4][rsel:16][8].
//   addr(row, e) = (row>>4)*2048 + (e>>5)*512 + ((e>>3)&3)*128 + (row&15)*8 + (e&7)
// A wave's MFMA fragment load (rsel=lane&15, kgrp=lane>>4, 8 elems at
// e = kk*32 + kgrp*8) becomes  panel*2048 + kk*512 + lane*8  -- 64 lanes x 16B
// CONTIGUOUS 1KiB, 16 cache lines/instr. The old row-major gather touched 64
// distinct 64B lines per instr (16 rows per 16-lane exec group, zero intra-
// group coalescing) -> ~1536 TA-cycles/tile -> the invariant ~40us/CU wall
// that no occupancy/pipelining change could move (r6-r10).
__global__ __launch_bounds__(256) void normalize_kernel(const float* __restrict__ feat,
                                                        const int* __restrict__ labels,
                                                        unsigned short* __restrict__ fb2,
                                                        unsigned char* __restrict__ lab8) {
  const int gid = blockIdx.x * 256 + threadIdx.x;
  if (gid < N_PTS) lab8[gid] = (unsigned char)labels[gid];
  const int row = blockIdx.x * 8 + (threadIdx.x >> 5);
  const int l32 = threadIdx.x & 31;
  const float4 v = *(const float4*)(feat + row * DIM + l32 * 4);
  float ss = v.x * v.x + v.y * v.y + v.z * v.z + v.w * v.w;
#pragma unroll
  for (int o = 16; o > 0; o >>= 1) ss += __shfl_xor(ss, o);  // stays in 32-group
  const float inv = 1.0f / fmaxf(sqrtf(ss), 1e-12f);
  uint2 pack;
  pack.x = (unsigned int)f2bf(v.x * inv) | ((unsigned int)f2bf(v.y * inv) << 16);
  pack.y = (unsigned int)f2bf(v.z * inv) | ((unsigned int)f2bf(v.w * inv) << 16);
  const int e0 = l32 * 4;  // elems e0..e0+3 (one 8B half of a 16B chunk)
  const int dst = (row >> 4) * 2048 + (e0 >> 5) * 512 + ((e0 >> 3) & 3) * 128 +
                  (row & 15) * 8 + (e0 & 7);
  *(uint2*)(fb2 + dst) = pack;  // 8B aligned: dst*2 is a multiple of 8
}

// ---- tile machinery (verified r7-r10) ----
#define OFFI(I) (128 * (I) - (((I) - 1) * ((I) - 1)) / 4)
#define DECODE(TID, IV, JV)                                              \
  do {                                                                   \
    int _i = (int)(2.0f * (128.5f - sqrtf(16512.0f - (float)(TID))));    \
    _i = _i < 0 ? 0 : (_i > 255 ? 255 : _i);                             \
    while (OFFI(_i) > (TID)) --_i;                                       \
    while (OFFI(_i + 1) <= (TID)) ++_i;                                  \
    IV = _i;                                                             \
    JV = (_i >> 1) + ((TID)-OFFI(_i));                                   \
  } while (0)

// Wave-independent 32x64 tiles, zero LDS, zero barriers, single-buffered
// K-loop — byte-identical structure to the r7 kernel (56.4us baseline);
// the ONLY change this round is the panel-swizzled fragment loads.
__global__ __launch_bounds__(256) void pair_kernel(const unsigned short* __restrict__ f,
                                                   const unsigned char* __restrict__ lab8,
                                                   float4* __restrict__ partials) {
  const int lane = threadIdx.x & 63;
  const int tid = blockIdx.x * 4 + (threadIdx.x >> 6);  // tile id, 0..NBLK-1

  int I, J;
  DECODE(tid, I, J);

  const int rsel = lane & 15, kgrp = lane >> 4;

  // panel-swizzled fragment pointers: contiguous 1KiB per fragment load
  const unsigned short* pA = f + (size_t)(I * 2) * 2048 + lane * 8;
  const unsigned short* pB = f + (size_t)(J * 4) * 2048 + lane * 8;

  // epilogue label gathers issued early; latency hides under the K-loop
  const int ibase = I * 32 + kgrp * 4;
  const int jbase = J * 64 + rsel;
  unsigned int liPack[2], ljPack = 0;
#pragma unroll
  for (int tn = 0; tn < 4; ++tn)
    ljPack |= ((unsigned int)lab8[jbase + tn * 16]) << (tn * 8);
#pragma unroll
  for (int tm = 0; tm < 2; ++tm)
    liPack[tm] = *(const unsigned int*)(lab8 + ibase + tm * 16);

  f32x4 acc[2][4];
#pragma unroll
  for (int a = 0; a < 2; ++a)
#pragma unroll
    for (int b = 0; b < 4; ++b) acc[a][b] = (f32x4){0.f, 0.f, 0.f, 0.f};

#pragma unroll 1
  for (int kk = 0; kk < 4; ++kk) {
    bf16x8 fa[2], fbv[4];
#pragma unroll
    for (int x = 0; x < 2; ++x) fa[x] = *(const bf16x8*)(pA + x * 2048 + kk * 512);
#pragma unroll
    for (int x = 0; x < 4; ++x) fbv[x] = *(const bf16x8*)(pB + x * 2048 + kk * 512);
#pragma unroll
    for (int tm = 0; tm < 2; ++tm)
#pragma unroll
      for (int tn = 0; tn < 4; ++tn)
        acc[tm][tn] =
            __builtin_amdgcn_mfma_f32_16x16x32_bf16(fa[tm], fbv[tn], acc[tm][tn], 0, 0, 0);
  }

  // ---- epilogue: circle-loss logits (base-2 domain) + in-wave logsumexp ----
  // C/D mapping (16x16x32): col = lane&15 (j/B side), row = (lane>>4)*4 + reg

  // pass 1: selected logit in-place, per-thread maxes
  float mp = NEGH, mn = NEGH;
  if (2 * J > I) {  // tile fully above the diagonal: all pairs valid (j > i)
#pragma unroll
    for (int tm = 0; tm < 2; ++tm)
#pragma unroll
      for (int tn = 0; tn < 4; ++tn) {
        const unsigned int ljB = (ljPack >> (tn * 8)) & 0xFFu;
#pragma unroll
        for (int r = 0; r < 4; ++r) {
          const float s = acc[tm][tn][r];
          const bool eq = (((liPack[tm] >> (r * 8)) & 0xFFu) == ljB);
          float u = fmaf(s, fmaf(s, KC2, eq ? KC1 : 0.f), eq ? KC0 : KCN0);
          u = (!eq && s <= -0.25f) ? 0.f : u;
          acc[tm][tn][r] = u;
          mp = fmaxf(mp, eq ? u : NEGH);
          mn = fmaxf(mn, eq ? NEGH : u);
        }
      }
  } else {  // diagonal-straddling tile: mask out j <= i
#pragma unroll
    for (int tm = 0; tm < 2; ++tm)
#pragma unroll
      for (int tn = 0; tn < 4; ++tn) {
        const unsigned int ljB = (ljPack >> (tn * 8)) & 0xFFu;
        const int d = (jbase + tn * 16) - (ibase + tm * 16);  // valid iff d > r
#pragma unroll
        for (int r = 0; r < 4; ++r) {
          const float s = acc[tm][tn][r];
          const bool eq = (((liPack[tm] >> (r * 8)) & 0xFFu) == ljB);
          float u = fmaf(s, fmaf(s, KC2, eq ? KC1 : 0.f), eq ? KC0 : KCN0);
          u = (!eq && s <= -0.25f) ? 0.f : u;
          const bool valid = d > r;
          u = valid ? u : NEGH;
          acc[tm][tn][r] = u;
          mp = fmaxf(mp, (eq && valid) ? u : NEGH);
          mn = fmaxf(mn, (!eq && valid) ? u : NEGH);
        }
      }
  }
  // in-wave butterfly: all 64 lanes end with the wave max (no LDS, no barrier)
#pragma unroll
  for (int o = 32; o > 0; o >>= 1) {
    mp = fmaxf(mp, __shfl_xor(mp, o));
    mn = fmaxf(mn, __shfl_xor(mn, o));
  }
  // Clamp keeps exp2(NEGH - M) == 0 even when a stream is empty in this tile.
  const float Mp = fmaxf(mp, -1e28f);
  const float Mn = fmaxf(mn, -1e28f);

  // pass 2: one exp2 per element, route to the owning stream
  float sp = 0.f, sn = 0.f;
#pragma unroll
  for (int tm = 0; tm < 2; ++tm)
#pragma unroll
    for (int tn = 0; tn < 4; ++tn) {
      const unsigned int ljB = (ljPack >> (tn * 8)) & 0xFFu;
#pragma unroll
      for (int r = 0; r < 4; ++r) {
        const bool eq = (((liPack[tm] >> (r * 8)) & 0xFFu) == ljB);
        const float e = __builtin_amdgcn_exp2f(acc[tm][tn][r] - (eq ? Mp : Mn));
        sp += eq ? e : 0.f;
        sn += eq ? 0.f : e;
      }
    }
#pragma unroll
  for (int o = 32; o > 0; o >>= 1) {
    sp += __shfl_xor(sp, o);
    sn += __shfl_xor(sn, o);
  }
  if (lane == 0) partials[tid] = make_float4(Mp, sp, Mn, sn);
}

// Merge 16512 (m2,s2) base-2 partials for both streams; softplus(lse_p+lse_n).
__global__ __launch_bounds__(1024) void finalize_kernel(const float4* __restrict__ partials,
                                                        float* __restrict__ out) {
  const int t = threadIdx.x;
  float mp = NEGH, sp = 0.f, mn = NEGH, sn = 0.f;
  for (int i = t; i < NBLK; i += 1024) {
    const float4 p = partials[i];
    {
      const float m = fmaxf(mp, p.x);
      sp = sp * __builtin_amdgcn_exp2f(mp - m) + p.y * __builtin_amdgcn_exp2f(p.x - m);
      mp = m;
    }
    {
      const float m = fmaxf(mn, p.z);
      sn = sn * __builtin_amdgcn_exp2f(mn - m) + p.w * __builtin_amdgcn_exp2f(p.z - m);
      mn = m;
    }
  }
  __shared__ float smp[1024], ssp[1024], smn[1024], ssn[1024];
  smp[t] = mp; ssp[t] = sp; smn[t] = mn; ssn[t] = sn;
  __syncthreads();
  for (int off = 512; off > 0; off >>= 1) {
    if (t < off) {
      {
        const float m2 = smp[t + off], s2 = ssp[t + off];
        const float m = fmaxf(smp[t], m2);
        ssp[t] = ssp[t] * __builtin_amdgcn_exp2f(smp[t] - m) + s2 * __builtin_amdgcn_exp2f(m2 - m);
        smp[t] = m;
      }
      {
        const float m2 = smn[t + off], s2 = ssn[t + off];
        const float m = fmaxf(smn[t], m2);
        ssn[t] = ssn[t] * __builtin_amdgcn_exp2f(smn[t] - m) + s2 * __builtin_amdgcn_exp2f(m2 - m);
        smn[t] = m;
      }
    }
    __syncthreads();
  }
  if (t == 0) {
    const float lsep = (smp[0] + __builtin_amdgcn_logf(ssp[0])) * LN2F;  // base-2 -> nat
    const float lsen = (smn[0] + __builtin_amdgcn_logf(ssn[0])) * LN2F;
    const float x = lsep + lsen;
    out[0] = fmaxf(x, 0.f) + log1pf(__expf(-fabsf(x)));  // stable softplus
  }
}

extern "C" void kernel_launch(void* const* d_in, const int* in_sizes, int n_in,
                              void* d_out, int out_size, void* d_ws, size_t ws_size,
                              hipStream_t stream) {
  const float* feat = (const float*)d_in[0];
  const int* labels = (const int*)d_in[1];
  float* out = (float*)d_out;

  unsigned short* fb2 = (unsigned short*)d_ws;                       // 2 MiB (panel-swizzled)
  char* base = (char*)d_ws + (size_t)N_PTS * DIM * 2;
  float4* partials = (float4*)base;                                  // 16512*16 = 258 KiB
  unsigned char* lab8 = (unsigned char*)(base + (size_t)NBLK * 16);  // 8192 B

  normalize_kernel<<<N_PTS / 8, 256, 0, stream>>>(feat, labels, fb2, lab8);
  pair_kernel<<<NBLK / 4, 256, 0, stream>>>(fb2, lab8, partials);
  finalize_kernel<<<1, 1024, 0, stream>>>(partials, out);
}